// Round 11
// baseline (692.038 us; speedup 1.0000x reference)
//
#include <hip/hip_runtime.h>
#include <hip/hip_bf16.h>
#include <stdint.h>

typedef float f32x4  __attribute__((ext_vector_type(4)));
typedef float f32x16 __attribute__((ext_vector_type(16)));
typedef int   i32x4  __attribute__((ext_vector_type(4)));
typedef int   i32x8  __attribute__((ext_vector_type(8)));
typedef unsigned char uchar;

#define B_ 2
#define C_ 512
#define N_ 4096
#define G_ 32
#define WN (C_ * C_)
#define NBLK 512

static constexpr long long sHn = (long long)N_ * C_;   // bytes (fp8)
static constexpr long long sQK = (long long)N_ * 1024;
static constexpr long long sV  = (long long)C_ * N_;
static constexpr long long sS  = (long long)N_ * N_;

static __device__ __forceinline__ short f2bf(float f) {
    return __builtin_bit_cast(short, __float2bfloat16(f));
}
static __device__ __forceinline__ uchar f2fp8(float f) {
    return (uchar)(__builtin_amdgcn_cvt_pk_fp8_f32(f, f, 0, false) & 0xff);
}
static __device__ __forceinline__ unsigned pk4fp8(float a, float b, float c, float d) {
    int w = __builtin_amdgcn_cvt_pk_fp8_f32(a, b, 0, false);
    w = __builtin_amdgcn_cvt_pk_fp8_f32(c, d, w, true);
    return (unsigned)w;
}

// async global->LDS DMA, 16 B/lane. LDS dest = wave-uniform base + lane*16.
static __device__ __forceinline__ void async16(uchar* lds_wave_base, const uchar* g) {
    auto l  = (__attribute__((address_space(3))) unsigned int*)(uintptr_t)(lds_wave_base);
    auto gg = (const __attribute__((address_space(1))) unsigned int*)(g);
    __builtin_amdgcn_global_load_lds(gg, l, 16, 0, 0);
}

// ---- software grid barrier (all NBLK blocks guaranteed co-resident:
// LDS 48KB -> 2 blk/CU, launch_bounds(256,2) -> <=256 VGPR -> 8 waves/CU;
// 256 CUs x 2 = 512 = grid). Monotonic counter, no reset; zeroed by a
// pre-launch hipMemsetAsync. Release fence (L2 writeback) before arrival,
// acquire fence (L2 invalidate) after release — same coherence a kernel
// boundary provides on non-coherent per-XCD L2s.
static __device__ __forceinline__ void gridbar(unsigned* cnt, unsigned target) {
    __syncthreads();
    __threadfence();                 // release: flush this block's writes
    __syncthreads();                 // all threads' fences complete
    if (threadIdx.x == 0) {
        atomicAdd(cnt, 1u);
        while (atomicAdd(cnt, 0u) < target)
            __builtin_amdgcn_s_sleep(8);
    }
    __syncthreads();
    __threadfence();                 // acquire: invalidate stale lines
}

// ---- fp8 NT GEMM body, MX-scaled MFMA (32x32x64 f8f6f4, unit scales) ----
// (byte-identical to R9's proven body)
// SCALE CONVENTION: Wb = fp8(16*w); Hn = fp8(hn); V8 = fp8(v); Sb = fp8(p);
//   Ot8 = fp8(16*o)  [proj: (16w)(16o)/256 = w*o].
// OUT_MODE: 2 fp32+res, 3 fp8, 5 PV rowsum-via-ones-MFMA, 6 S->P no-max exp.
template<int BM, int BN, int BIAS_MODE, int OUT_MODE, int K>
static __device__ __forceinline__ void gemm_body(
        uchar* As_, uchar* Bs_,                      // [3][BM*64], [3][BN*64]
        int bx, int by, int bz,
        const uchar* __restrict__ A, int lda, long long sAz,
        const uchar* __restrict__ Bm, int ldb, long long sBz,
        void* __restrict__ Cv, int ldc, long long sCz,
        const float* __restrict__ bias,
        const void* __restrict__ resv,
        float alpha) {
    constexpr int MI = BM / 64;
    constexpr int NI = BN / 64;
    constexpr int AC = BM / 64;
    constexpr int BC = BN / 64;
    constexpr int T  = K / 64;
    constexpr int D  = (BM + BN) / 64;
    constexpr unsigned WAITD = 0xF70u | D;           // vmcnt(D) expcnt(7) lgkm(15)
    constexpr unsigned WAIT0 = 0xF70u;               // vmcnt(0)
    constexpr int ASZ = BM * 64, BSZ = BN * 64;

    const int tid  = threadIdx.x;
    const int lane = tid & 63;
    const int wid  = tid >> 6;
    const int wr   = wid >> 1;
    const int wc   = wid & 1;
    const int m0 = by * BM;
    const int n0 = bx * BN;

    const int r  = tid >> 2;
    const int gc = (tid & 3) ^ ((r >> 1) & 3);
    const uchar* Ap = A  + sAz * bz + (size_t)(m0 + r) * lda + gc * 16;
    const uchar* Bp = Bm + sBz * bz + (size_t)(n0 + r) * ldb + gc * 16;

    f32x16 acc[MI][NI];
    #pragma unroll
    for (int i = 0; i < MI; i++)
        #pragma unroll
        for (int j = 0; j < NI; j++)
            #pragma unroll
            for (int e = 0; e < 16; e++)
                acc[i][j][e] = 0.f;

    f32x16 accs[MI];
    i32x8 ones8;
    if (OUT_MODE == 5) {
        #pragma unroll
        for (int i = 0; i < MI; i++)
            #pragma unroll
            for (int e = 0; e < 16; e++)
                accs[i][e] = 0.f;
        #pragma unroll
        for (int e = 0; e < 8; e++)
            ones8[e] = 0x38383838;                   // fp8 e4m3 1.0 x4
    }

    const int rl = lane & 31;
    const int hk = (lane >> 5) * 2;

    #define ISSUE(IB, u) do { size_t _kb = (size_t)(u) * 64; \
        _Pragma("unroll") \
        for (int c = 0; c < AC; c++) \
            async16(As_ + (IB)*ASZ + c * 4096 + wid * 1024, Ap + (size_t)c * 64 * lda + _kb); \
        _Pragma("unroll") \
        for (int c = 0; c < BC; c++) \
            async16(Bs_ + (IB)*BSZ + c * 4096 + wid * 1024, Bp + (size_t)c * 64 * ldb + _kb); } while (0)

    #define STEP(Bf, DO_ISSUE, IB, u, DO_BAR, WIMM) do { \
        i32x8 af[MI], bf[NI]; \
        _Pragma("unroll") \
        for (int i = 0; i < MI; i++) { \
            int ar = wr*(BM/2) + i*32 + rl; \
            int ao = ar*64 + ((hk ^ ((ar>>1)&3)) << 4); \
            *(i32x4*)&af[i]       = *(const i32x4*)(As_ + (Bf)*ASZ + ao); \
            *(((i32x4*)&af[i])+1) = *(const i32x4*)(As_ + (Bf)*ASZ + (ao ^ 16)); \
        } \
        _Pragma("unroll") \
        for (int i = 0; i < NI; i++) { \
            int br = wc*(BN/2) + i*32 + rl; \
            int bo = br*64 + ((hk ^ ((br>>1)&3)) << 4); \
            *(i32x4*)&bf[i]       = *(const i32x4*)(Bs_ + (Bf)*BSZ + bo); \
            *(((i32x4*)&bf[i])+1) = *(const i32x4*)(Bs_ + (Bf)*BSZ + (bo ^ 16)); \
        } \
        if (DO_ISSUE) ISSUE(IB, u); \
        _Pragma("unroll") \
        for (int mi = 0; mi < MI; mi++) \
            _Pragma("unroll") \
            for (int ni = 0; ni < NI; ni++) \
                acc[mi][ni] = __builtin_amdgcn_mfma_scale_f32_32x32x64_f8f6f4( \
                    af[mi], bf[ni], acc[mi][ni], 0, 0, 0, 127, 0, 127); \
        if (OUT_MODE == 5) { \
            _Pragma("unroll") \
            for (int mi = 0; mi < MI; mi++) \
                accs[mi] = __builtin_amdgcn_mfma_scale_f32_32x32x64_f8f6f4( \
                    af[mi], ones8, accs[mi], 0, 0, 0, 127, 0, 127); \
        } \
        if (DO_BAR) { __builtin_amdgcn_s_waitcnt(WIMM); __builtin_amdgcn_s_barrier(); } \
    } while (0)

    ISSUE(0, 0);
    ISSUE(1, 1);
    __builtin_amdgcn_s_waitcnt(WAITD);
    __builtin_amdgcn_s_barrier();

    constexpr int Gm = (T - 2) / 3;
    for (int m = 0; m < Gm; m++) {
        STEP(0, 1, 2, m*3 + 2, 1, WAITD);
        STEP(1, 1, 0, m*3 + 3, 1, WAITD);
        STEP(2, 1, 1, m*3 + 4, 1, WAITD);
    }
    if (T - 3*Gm == 2) {                             // T=8
        STEP(0, 0, 0, 0, 1, WAIT0);
        STEP(1, 0, 0, 0, 0, 0);
    } else {                                         // T=64
        STEP(0, 1, 2, T-2, 1, WAITD);
        STEP(1, 1, 0, T-1, 1, WAITD);
        STEP(2, 0, 0, 0, 1, WAIT0);
        STEP(0, 0, 0, 0, 0, 0);
    }
    #undef ISSUE
    #undef STEP

    const int rh = (lane >> 5) * 4;

    if (OUT_MODE == 6) {
        #pragma unroll
        for (int mi = 0; mi < MI; mi++) {
            #pragma unroll
            for (int ni = 0; ni < NI; ni++) {
                int cc = n0 + wc*(BN/2) + ni*32 + rl;
                #pragma unroll
                for (int e = 0; e < 16; e++) {
                    int g = e >> 2, r4 = e & 3;
                    int rr = m0 + wr*(BM/2) + mi*32 + g*8 + rh + r4;
                    float p = fminf(__expf(acc[mi][ni][e] * alpha), 448.f);
                    long long idx = sCz * bz + (long long)rr * ldc + cc;
                    ((uchar*)Cv)[idx] = f2fp8(p);
                }
            }
        }
        return;
    }

    if (OUT_MODE == 5) {
        #pragma unroll
        for (int mi = 0; mi < MI; mi++) {
            #pragma unroll
            for (int e = 0; e < 16; e++) {
                int g = e >> 2, r4 = e & 3;
                int rr = m0 + wr*(BM/2) + mi*32 + g*8 + rh + r4;
                float rinv = __builtin_amdgcn_rcpf(accs[mi][e]) * alpha;
                #pragma unroll
                for (int ni = 0; ni < NI; ni++) {
                    int cc = n0 + wc*(BN/2) + ni*32 + rl;
                    long long idx = sCz * bz + (long long)rr * ldc + cc;
                    ((uchar*)Cv)[idx] = f2fp8(acc[mi][ni][e] * rinv);
                }
            }
        }
        return;
    }

    #pragma unroll
    for (int mi = 0; mi < MI; mi++) {
        #pragma unroll
        for (int ni = 0; ni < NI; ni++) {
            int cc = n0 + wc*(BN/2) + ni*32 + rl;
            float cb = (BIAS_MODE == 1) ? bias[cc] : 0.f;
            #pragma unroll
            for (int g = 0; g < 4; g++) {
                #pragma unroll
                for (int r4 = 0; r4 < 4; r4++) {
                    int rr = m0 + wr*(BM/2) + mi*32 + g*8 + rh + r4;
                    float val = acc[mi][ni][g*4 + r4] * alpha + cb;
                    if (BIAS_MODE == 2) val += bias[rr];
                    long long idx = sCz * bz + (long long)rr * ldc + cc;
                    if (OUT_MODE == 0)      ((short*)Cv)[idx] = f2bf(val);
                    else if (OUT_MODE == 2) ((float*)Cv)[idx] = val + ((const float*)resv)[idx];
                    else                    ((uchar*)Cv)[idx] = f2fp8(val);
                }
            }
        }
    }
}

// ---- persistent mega-kernel: all 6 phases, software grid barrier between ----
// 512 blocks x 256 threads, plain launch (no cooperative API). Phase decodes
// identical to R9 (fid = b0 + k*512 preserves fid&7 -> XCD affinity intact).
__global__ __launch_bounds__(256, 2)
void mega(const float* __restrict__ x, const float* __restrict__ gnw,
          const float* __restrict__ gnb,
          const float* __restrict__ wq, const float* __restrict__ bq,
          const float* __restrict__ wk, const float* __restrict__ bk,
          const float* __restrict__ wv, const float* __restrict__ bv,
          const float* __restrict__ wp, const float* __restrict__ bp,
          float* __restrict__ out,
          uchar* __restrict__ Wb, float* __restrict__ bqkv,
          float* __restrict__ raw, unsigned* __restrict__ bar,
          uchar* __restrict__ Hn, uchar* __restrict__ QK8,
          uchar* __restrict__ V8, uchar* __restrict__ Ot8,
          uchar* __restrict__ Sb) {
    __shared__ uchar smem[49152];
    const int b0  = blockIdx.x;                      // 0..511
    const int tid = threadIdx.x;

    // ===== phase 0: weight fp8 convert + bqkv + gn partial stats =====
    if (b0 >= 256) {
        int wb = b0 - 256;                           // 0..255
        #pragma unroll
        for (int it = 0; it < 4; it++) {
            int i4 = (it * 256 + wb) * 256 + tid;    // < 262144
            int base = i4 * 4;
            int wsel = base >> 18;
            const float* src = (wsel == 0) ? wq : (wsel == 1) ? wk : (wsel == 2) ? wv : wp;
            float4 t = *(const float4*)(src + (base & (WN - 1)));
            ((unsigned*)Wb)[i4] = pk4fp8(t.x*16.f, t.y*16.f, t.z*16.f, t.w*16.f);
        }
        if (b0 == 511) {
            for (int j = tid; j < 1536; j += 256)
                bqkv[j] = (j < C_) ? bq[j] : (j < 2*C_) ? bk[j - C_] : bv[j - 2*C_];
        }
    } else {
        const int bg = b0 >> 2, qt = b0 & 3;
        const float4* p = (const float4*)(x + (size_t)bg * 16 * N_ + (size_t)qt * 4 * N_);
        float s = 0.f, sq = 0.f;
        #pragma unroll
        for (int rep = 0; rep < 16; rep++) {
            float4 t = p[rep * 256 + tid];
            s  += t.x + t.y + t.z + t.w;
            sq += t.x*t.x + t.y*t.y + t.z*t.z + t.w*t.w;
        }
        float* rs = (float*)smem;
        float* rq = (float*)(smem + 1024);
        rs[tid] = s; rq[tid] = sq;
        __syncthreads();
        for (int h = 128; h > 0; h >>= 1) {
            if (tid < h) { rs[tid] += rs[tid+h]; rq[tid] += rq[tid+h]; }
            __syncthreads();
        }
        if (tid == 0) {
            raw[b0*2+0] = rs[0];
            raw[b0*2+1] = rq[0];
        }
    }
    gridbar(bar, 1 * NBLK);

    // ===== phase 1: groupnorm apply + transpose (2 tiles/block) =====
    {
        uchar* t = smem;                             // [64*68]
        const int lane = tid & 63, w = tid >> 6;
        const float inv = 1.f / (16.f * N_);
        #pragma unroll
        for (int u = 0; u < 2; u++) {
            int fid = b0 + u * 512;
            int xcd = fid & 7, j = fid >> 3;
            int n0 = ((xcd << 3) | (j & 7)) * 64;
            int c0 = ((j >> 3) & 7) * 64;
            int b  = j >> 6;
            #pragma unroll
            for (int rep = 0; rep < 16; rep++) {
                int c  = rep * 4 + w;
                int cc = c0 + c;
                int g  = cc >> 4;
                int base = (b*G_ + g) * 8;
                float mean = (raw[base] + raw[base+2] + raw[base+4] + raw[base+6]) * inv;
                float var  = (raw[base+1] + raw[base+3] + raw[base+5] + raw[base+7]) * inv - mean * mean;
                float rstd = rsqrtf(var + 1e-6f);
                float sc = gnw[cc] * rstd;
                float bi = gnb[cc] - mean * sc;
                float v = x[((size_t)(b*C_ + cc)) * N_ + n0 + lane];
                t[lane*68 + c] = f2fp8(v * sc + bi);
            }
            __syncthreads();
            #pragma unroll
            for (int rep = 0; rep < 16; rep++) {
                int n = rep * 4 + w;
                Hn[((size_t)(b*N_ + n0 + n)) * C_ + c0 + lane] = t[n*68 + lane];
            }
            __syncthreads();
        }
    }
    gridbar(bar, 2 * NBLK);

    // ===== phase 2: QK tile then V tile =====
    {
        int xcd = b0 & 7, j = b0 >> 3;               // j 0..63
        {   // QK: [4096,1024] = (Hn @ [Wq;Wk]^T)/16 + bqk -> fp8
            int by = (xcd << 2) | (j & 3);
            int bx = (j >> 2) & 7, bz = j >> 5;
            gemm_body<128,128,1,3,512>(smem, smem + 3*128*64, bx, by, bz,
                Hn, C_, sHn, Wb, C_, 0, QK8, 1024, sQK, bqkv, nullptr, 1.f/16.f);
        }
        __syncthreads();
        {   // V: [512,4096] = (Wv @ Hn^T)/16 + bv -> fp8(v)
            int bx = (xcd << 2) | (j & 3);
            int by = (j >> 2) & 7, bz = j >> 5;
            gemm_body<64,128,2,3,512>(smem, smem + 3*64*64, bx, by, bz,
                Wb + 2*WN, C_, 0, Hn, C_, sHn, V8, N_, sV, bqkv + 1024, nullptr, 1.f/16.f);
        }
    }
    gridbar(bar, 3 * NBLK);

    // ===== phase 3: S = exp(QK^T/sqrt(512)) -> fp8, 4 tiles/block =====
    for (int it = 0; it < 4; it++) {
        int fid = b0 + it * 512;
        int xcd = fid & 7, j = fid >> 3;             // j 0..255
        int bz = j >> 7;
        int r = j & 127;
        int by = (xcd << 2) | (r >> 5);
        int bx = r & 31;
        gemm_body<128,128,0,6,512>(smem, smem + 3*128*64, bx, by, bz,
            QK8, 1024, sQK, QK8 + 512, 1024, sQK, Sb, N_, sS, nullptr, nullptr,
            0.044194173824159216f);
        __syncthreads();
    }
    gridbar(bar, 4 * NBLK);

    // ===== phase 4: PV: Ot = 16*(P@V^T)/rowsum(P) =====
    {
        int xcd = b0 & 7, j = b0 >> 3;               // j 0..63
        int by = (xcd << 3) | (j & 7);
        int bx = (j >> 3) & 3, bz = j >> 5;
        gemm_body<64,128,0,5,4096>(smem, smem + 3*64*64, bx, by, bz,
            Sb, N_, sS, V8, N_, sV, Ot8, C_, sHn, nullptr, nullptr, 16.f);
    }
    gridbar(bar, 5 * NBLK);

    // ===== phase 5: proj: out = x + Wp@Ot^T/256 + bp =====
    {
        int xcd = b0 & 7, j = b0 >> 3;               // j 0..63
        int bx = (xcd << 2) | (j & 3);
        int by = (j >> 2) & 7, bz = j >> 5;
        gemm_body<64,128,2,2,512>(smem, smem + 3*64*64, bx, by, bz,
            Wb + 3*WN, C_, 0, Ot8, C_, sHn, out, N_, (long long)C_ * N_, bp, x, 1.f/256.f);
    }
}

extern "C" void kernel_launch(void* const* d_in, const int* in_sizes, int n_in,
                              void* d_out, int out_size, void* d_ws, size_t ws_size,
                              hipStream_t stream) {
    const float* x   = (const float*)d_in[0];
    const float* gnw = (const float*)d_in[1];
    const float* gnb = (const float*)d_in[2];
    const float* wq  = (const float*)d_in[3];
    const float* bq  = (const float*)d_in[4];
    const float* wk  = (const float*)d_in[5];
    const float* bk  = (const float*)d_in[6];
    const float* wv  = (const float*)d_in[7];
    const float* bv  = (const float*)d_in[8];
    const float* wp  = (const float*)d_in[9];
    const float* bp  = (const float*)d_in[10];
    float* out = (float*)d_out;
    char*  ws  = (char*)d_ws;

    // workspace layout (~56 MB)
    float*    raw  = (float*)(ws + 0);               // 2 KB  gn stat partials
    unsigned* bar  = (unsigned*)(ws + 4096);         // 64 B  grid-barrier counter
    float*    bqkv = (float*)(ws + 8192);            // 6 KB  bq|bk|bv
    uchar* Wb  = (uchar*)(ws + 65536);               // 1 MB  [4][512][512] fp8 (x16)
    uchar* Hn  = (uchar*)(ws + (2ull  << 20));       // 4 MB  [2][4096][512] fp8
    uchar* QK8 = (uchar*)(ws + (8ull  << 20));       // 8 MB  [2][4096][1024] fp8 (Q|K)
    uchar* V8  = (uchar*)(ws + (16ull << 20));       // 4 MB  [2][512][4096] fp8 (v)
    uchar* Ot8 = (uchar*)(ws + (20ull << 20));       // 4 MB  [2][4096][512] fp8 (16*o)
    uchar* Sb  = (uchar*)(ws + (24ull << 20));       // 32 MB [2][4096][4096] fp8 (P)

    hipMemsetAsync(bar, 0, 64, stream);              // zero barrier counter (ws is poisoned)
    mega<<<NBLK, 256, 0, stream>>>(x, gnw, gnb, wq, bq, wk, bk, wv, bv, wp, bp,
                                   out, Wb, bqkv, raw, bar,
                                   Hn, QK8, V8, Ot8, Sb);
}

// Round 12
// 169.656 us; speedup vs baseline: 4.0791x; 4.0791x over previous
//
#include <hip/hip_runtime.h>
#include <hip/hip_bf16.h>
#include <stdint.h>

typedef float f32x4  __attribute__((ext_vector_type(4)));
typedef float f32x16 __attribute__((ext_vector_type(16)));
typedef int   i32x4  __attribute__((ext_vector_type(4)));
typedef int   i32x8  __attribute__((ext_vector_type(8)));
typedef unsigned char uchar;

#define B_ 2
#define C_ 512
#define N_ 4096
#define G_ 32
#define WN (C_ * C_)
#define PREP_W 1024          // 4*WN/4 float4 loads / 256
#define PREP_BLOCKS 1030     // + 6 bias blocks (1536 floats)

static constexpr long long sHn = (long long)N_ * C_;   // bytes (fp8)
static constexpr long long sQK = (long long)N_ * 1024;
static constexpr long long sV  = (long long)C_ * N_;
static constexpr long long sS  = (long long)N_ * N_;

static __device__ __forceinline__ short f2bf(float f) {
    return __builtin_bit_cast(short, __float2bfloat16(f));
}
static __device__ __forceinline__ uchar f2fp8(float f) {
    return (uchar)(__builtin_amdgcn_cvt_pk_fp8_f32(f, f, 0, false) & 0xff);
}
static __device__ __forceinline__ unsigned pk4fp8(float a, float b, float c, float d) {
    int w = __builtin_amdgcn_cvt_pk_fp8_f32(a, b, 0, false);
    w = __builtin_amdgcn_cvt_pk_fp8_f32(c, d, w, true);
    return (unsigned)w;
}

// async global->LDS DMA, 16 B/lane. LDS dest = wave-uniform base + lane*16.
static __device__ __forceinline__ void async16(uchar* lds_wave_base, const uchar* g) {
    auto l  = (__attribute__((address_space(3))) unsigned int*)(uintptr_t)(lds_wave_base);
    auto gg = (const __attribute__((address_space(1))) unsigned int*)(g);
    __builtin_amdgcn_global_load_lds(gg, l, 16, 0, 0);
}

// ---- merged prep + gn partial stats (no atomics: each stats block owns a slot) ----
__global__ void prep_stats(const float* __restrict__ wq, const float* __restrict__ wk,
                           const float* __restrict__ wv, const float* __restrict__ wp,
                           const float* __restrict__ bq, const float* __restrict__ bk,
                           const float* __restrict__ bv,
                           const float* __restrict__ x,
                           uchar* __restrict__ Wb, float* __restrict__ bqkv,
                           float* __restrict__ raw) {
    if (blockIdx.x < PREP_W) {                       // weights: float4 -> 4 fp8 (x16)
        int i4 = blockIdx.x * 256 + threadIdx.x;     // < 262144
        int base = i4 * 4;
        int wsel = base >> 18;
        const float* src = (wsel == 0) ? wq : (wsel == 1) ? wk : (wsel == 2) ? wv : wp;
        float4 t = *(const float4*)(src + (base & (WN - 1)));
        ((unsigned*)Wb)[i4] = pk4fp8(t.x*16.f, t.y*16.f, t.z*16.f, t.w*16.f);
        return;
    }
    if (blockIdx.x < PREP_BLOCKS) {                  // bqkv[1536] = bq|bk|bv
        int j = (blockIdx.x - PREP_W) * 256 + threadIdx.x;
        if (j < 1536)
            bqkv[j] = (j < C_) ? bq[j] : (j < 2*C_) ? bk[j - C_] : bv[j - 2*C_];
        return;
    }
    const int idx = blockIdx.x - PREP_BLOCKS;        // 0..255
    const int bg = idx >> 2, qt = idx & 3;
    const float4* p = (const float4*)(x + (size_t)bg * 16 * N_ + (size_t)qt * 4 * N_);
    int tid = threadIdx.x;
    float s = 0.f, sq = 0.f;
    #pragma unroll
    for (int rep = 0; rep < 16; rep++) {
        float4 t = p[rep * 256 + tid];
        s  += t.x + t.y + t.z + t.w;
        sq += t.x*t.x + t.y*t.y + t.z*t.z + t.w*t.w;
    }
    __shared__ float rs[256], rq[256];
    rs[tid] = s; rq[tid] = sq;
    __syncthreads();
    for (int h = 128; h > 0; h >>= 1) {
        if (tid < h) { rs[tid] += rs[tid+h]; rq[tid] += rq[tid+h]; }
        __syncthreads();
    }
    if (tid == 0) {
        raw[idx*2+0] = rs[0];
        raw[idx*2+1] = rq[0];
    }
}

// ---- groupnorm apply + transpose: x[b,c,n] fp32 -> Hn[b,n,c] fp8 ----
// Flat grid 1024, XCD-affine: XCD x writes Hn rows [512x, 512x+512).
__global__ void gn_apply(const float* __restrict__ x, const float* __restrict__ raw,
                         const float* __restrict__ gw, const float* __restrict__ gb,
                         uchar* __restrict__ hn) {
    __shared__ uchar t[64 * 68];
    const int fid = blockIdx.x;
    const int xcd = fid & 7, j = fid >> 3;           // j 0..127
    const int n0 = ((xcd << 3) | (j & 7)) * 64;
    const int c0 = ((j >> 3) & 7) * 64;
    const int b  = j >> 6;
    const int lane = threadIdx.x & 63, w = threadIdx.x >> 6;
    const float inv = 1.f / (16.f * N_);
    #pragma unroll
    for (int rep = 0; rep < 16; rep++) {
        int c  = rep * 4 + w;
        int cc = c0 + c;
        int g  = cc >> 4;
        int base = (b*G_ + g) * 8;
        float mean = (raw[base] + raw[base+2] + raw[base+4] + raw[base+6]) * inv;
        float var  = (raw[base+1] + raw[base+3] + raw[base+5] + raw[base+7]) * inv - mean * mean;
        float rstd = rsqrtf(var + 1e-6f);
        float sc = gw[cc] * rstd;
        float bi = gb[cc] - mean * sc;
        float v = x[((size_t)(b*C_ + cc)) * N_ + n0 + lane];
        t[lane*68 + c] = f2fp8(v * sc + bi);
    }
    __syncthreads();
    #pragma unroll
    for (int rep = 0; rep < 16; rep++) {
        int n = rep * 4 + w;
        hn[((size_t)(b*N_ + n0 + n)) * C_ + c0 + lane] = t[n*68 + lane];
    }
}

// ---- fp8 NT GEMM body, MX-scaled MFMA (32x32x64 f8f6f4, unit scales) ----
// (byte-identical to R9's proven body)
// SCALE CONVENTION: Wb = fp8(16*w); Hn = fp8(hn); V8 = fp8(v); Sb = fp8(p);
//   Ot8 = fp8(16*o)  [proj: (16w)(16o)/256 = w*o].
// OUT_MODE: 2 fp32+res, 3 fp8, 5 PV rowsum-via-ones-MFMA, 6 S->P no-max exp.
template<int BM, int BN, int BIAS_MODE, int OUT_MODE, int K>
static __device__ __forceinline__ void gemm_body(
        uchar* As_, uchar* Bs_,                      // [3][BM*64], [3][BN*64]
        int bx, int by, int bz,
        const uchar* __restrict__ A, int lda, long long sAz,
        const uchar* __restrict__ Bm, int ldb, long long sBz,
        void* __restrict__ Cv, int ldc, long long sCz,
        const float* __restrict__ bias,
        const void* __restrict__ resv,
        float alpha) {
    constexpr int MI = BM / 64;
    constexpr int NI = BN / 64;
    constexpr int AC = BM / 64;
    constexpr int BC = BN / 64;
    constexpr int T  = K / 64;
    constexpr int D  = (BM + BN) / 64;
    constexpr unsigned WAITD = 0xF70u | D;           // vmcnt(D) expcnt(7) lgkm(15)
    constexpr unsigned WAIT0 = 0xF70u;               // vmcnt(0)
    constexpr int ASZ = BM * 64, BSZ = BN * 64;

    const int tid  = threadIdx.x;
    const int lane = tid & 63;
    const int wid  = tid >> 6;
    const int wr   = wid >> 1;
    const int wc   = wid & 1;
    const int m0 = by * BM;
    const int n0 = bx * BN;

    const int r  = tid >> 2;
    const int gc = (tid & 3) ^ ((r >> 1) & 3);
    const uchar* Ap = A  + sAz * bz + (size_t)(m0 + r) * lda + gc * 16;
    const uchar* Bp = Bm + sBz * bz + (size_t)(n0 + r) * ldb + gc * 16;

    f32x16 acc[MI][NI];
    #pragma unroll
    for (int i = 0; i < MI; i++)
        #pragma unroll
        for (int j = 0; j < NI; j++)
            #pragma unroll
            for (int e = 0; e < 16; e++)
                acc[i][j][e] = 0.f;

    f32x16 accs[MI];
    i32x8 ones8;
    if (OUT_MODE == 5) {
        #pragma unroll
        for (int i = 0; i < MI; i++)
            #pragma unroll
            for (int e = 0; e < 16; e++)
                accs[i][e] = 0.f;
        #pragma unroll
        for (int e = 0; e < 8; e++)
            ones8[e] = 0x38383838;                   // fp8 e4m3 1.0 x4
    }

    const int rl = lane & 31;
    const int hk = (lane >> 5) * 2;

    #define ISSUE(IB, u) do { size_t _kb = (size_t)(u) * 64; \
        _Pragma("unroll") \
        for (int c = 0; c < AC; c++) \
            async16(As_ + (IB)*ASZ + c * 4096 + wid * 1024, Ap + (size_t)c * 64 * lda + _kb); \
        _Pragma("unroll") \
        for (int c = 0; c < BC; c++) \
            async16(Bs_ + (IB)*BSZ + c * 4096 + wid * 1024, Bp + (size_t)c * 64 * ldb + _kb); } while (0)

    #define STEP(Bf, DO_ISSUE, IB, u, DO_BAR, WIMM) do { \
        i32x8 af[MI], bf[NI]; \
        _Pragma("unroll") \
        for (int i = 0; i < MI; i++) { \
            int ar = wr*(BM/2) + i*32 + rl; \
            int ao = ar*64 + ((hk ^ ((ar>>1)&3)) << 4); \
            *(i32x4*)&af[i]       = *(const i32x4*)(As_ + (Bf)*ASZ + ao); \
            *(((i32x4*)&af[i])+1) = *(const i32x4*)(As_ + (Bf)*ASZ + (ao ^ 16)); \
        } \
        _Pragma("unroll") \
        for (int i = 0; i < NI; i++) { \
            int br = wc*(BN/2) + i*32 + rl; \
            int bo = br*64 + ((hk ^ ((br>>1)&3)) << 4); \
            *(i32x4*)&bf[i]       = *(const i32x4*)(Bs_ + (Bf)*BSZ + bo); \
            *(((i32x4*)&bf[i])+1) = *(const i32x4*)(Bs_ + (Bf)*BSZ + (bo ^ 16)); \
        } \
        if (DO_ISSUE) ISSUE(IB, u); \
        _Pragma("unroll") \
        for (int mi = 0; mi < MI; mi++) \
            _Pragma("unroll") \
            for (int ni = 0; ni < NI; ni++) \
                acc[mi][ni] = __builtin_amdgcn_mfma_scale_f32_32x32x64_f8f6f4( \
                    af[mi], bf[ni], acc[mi][ni], 0, 0, 0, 127, 0, 127); \
        if (OUT_MODE == 5) { \
            _Pragma("unroll") \
            for (int mi = 0; mi < MI; mi++) \
                accs[mi] = __builtin_amdgcn_mfma_scale_f32_32x32x64_f8f6f4( \
                    af[mi], ones8, accs[mi], 0, 0, 0, 127, 0, 127); \
        } \
        if (DO_BAR) { __builtin_amdgcn_s_waitcnt(WIMM); __builtin_amdgcn_s_barrier(); } \
    } while (0)

    ISSUE(0, 0);
    ISSUE(1, 1);
    __builtin_amdgcn_s_waitcnt(WAITD);
    __builtin_amdgcn_s_barrier();

    constexpr int Gm = (T - 2) / 3;
    for (int m = 0; m < Gm; m++) {
        STEP(0, 1, 2, m*3 + 2, 1, WAITD);
        STEP(1, 1, 0, m*3 + 3, 1, WAITD);
        STEP(2, 1, 1, m*3 + 4, 1, WAITD);
    }
    if (T - 3*Gm == 2) {                             // T=8
        STEP(0, 0, 0, 0, 1, WAIT0);
        STEP(1, 0, 0, 0, 0, 0);
    } else {                                         // T=64
        STEP(0, 1, 2, T-2, 1, WAITD);
        STEP(1, 1, 0, T-1, 1, WAITD);
        STEP(2, 0, 0, 0, 1, WAIT0);
        STEP(0, 0, 0, 0, 0, 0);
    }
    #undef ISSUE
    #undef STEP

    const int rh = (lane >> 5) * 4;

    if (OUT_MODE == 6) {
        #pragma unroll
        for (int mi = 0; mi < MI; mi++) {
            #pragma unroll
            for (int ni = 0; ni < NI; ni++) {
                int cc = n0 + wc*(BN/2) + ni*32 + rl;
                #pragma unroll
                for (int e = 0; e < 16; e++) {
                    int g = e >> 2, r4 = e & 3;
                    int rr = m0 + wr*(BM/2) + mi*32 + g*8 + rh + r4;
                    float p = fminf(__expf(acc[mi][ni][e] * alpha), 448.f);
                    long long idx = sCz * bz + (long long)rr * ldc + cc;
                    ((uchar*)Cv)[idx] = f2fp8(p);
                }
            }
        }
        return;
    }

    if (OUT_MODE == 5) {
        #pragma unroll
        for (int mi = 0; mi < MI; mi++) {
            #pragma unroll
            for (int e = 0; e < 16; e++) {
                int g = e >> 2, r4 = e & 3;
                int rr = m0 + wr*(BM/2) + mi*32 + g*8 + rh + r4;
                float rinv = __builtin_amdgcn_rcpf(accs[mi][e]) * alpha;
                #pragma unroll
                for (int ni = 0; ni < NI; ni++) {
                    int cc = n0 + wc*(BN/2) + ni*32 + rl;
                    long long idx = sCz * bz + (long long)rr * ldc + cc;
                    ((uchar*)Cv)[idx] = f2fp8(acc[mi][ni][e] * rinv);
                }
            }
        }
        return;
    }

    #pragma unroll
    for (int mi = 0; mi < MI; mi++) {
        #pragma unroll
        for (int ni = 0; ni < NI; ni++) {
            int cc = n0 + wc*(BN/2) + ni*32 + rl;
            float cb = (BIAS_MODE == 1) ? bias[cc] : 0.f;
            #pragma unroll
            for (int g = 0; g < 4; g++) {
                #pragma unroll
                for (int r4 = 0; r4 < 4; r4++) {
                    int rr = m0 + wr*(BM/2) + mi*32 + g*8 + rh + r4;
                    float val = acc[mi][ni][g*4 + r4] * alpha + cb;
                    if (BIAS_MODE == 2) val += bias[rr];
                    long long idx = sCz * bz + (long long)rr * ldc + cc;
                    if (OUT_MODE == 0)      ((short*)Cv)[idx] = f2bf(val);
                    else if (OUT_MODE == 2) ((float*)Cv)[idx] = val + ((const float*)resv)[idx];
                    else                    ((uchar*)Cv)[idx] = f2fp8(val);
                }
            }
        }
    }
}

// ---- merged QKV: 512 blocks; each block does its QK tile THEN its V tile ----
// (same per-tile decodes as R9/R11-phase-2, both correctness-proven; looping
// within the block amortizes the DMA-ring prologue and avoids a cold second
// occupancy round)
__global__ __launch_bounds__(256, 2)
void qkv_kernel(const uchar* __restrict__ Hn, const uchar* __restrict__ Wb,
                uchar* __restrict__ QK8, uchar* __restrict__ V8,
                const float* __restrict__ bqkv) {
    __shared__ uchar smem[49152];
    int b0 = blockIdx.x;                             // 0..511
    int xcd = b0 & 7, j = b0 >> 3;                   // j 0..63
    {   // QK: [4096,1024] = (Hn @ [Wq;Wk]^T)/16 + bqk -> fp8
        int by = (xcd << 2) | (j & 3);
        int bx = (j >> 2) & 7, bz = j >> 5;
        gemm_body<128,128,1,3,512>(smem, smem + 3*128*64, bx, by, bz,
            Hn, C_, sHn, Wb, C_, 0, QK8, 1024, sQK, bqkv, nullptr, 1.f/16.f);
    }
    __syncthreads();
    {   // V: [512,4096] = (Wv @ Hn^T)/16 + bv -> fp8(v)
        int bx = (xcd << 2) | (j & 3);
        int by = (j >> 2) & 7, bz = j >> 5;
        gemm_body<64,128,2,3,512>(smem, smem + 3*64*64, bx, by, bz,
            Wb + 2*WN, C_, 0, Hn, C_, sHn, V8, N_, sV, bqkv + 1024, nullptr, 1.f/16.f);
    }
}

// ---- S: P = exp(QK^T/sqrt(512)) -> fp8. 512 blocks x 4 tiles (R11 phase-3
// decode, proven): XCD x owns Sb rows band [512x, 512x+512). ----
__global__ __launch_bounds__(256, 2)
void s_kernel(const uchar* __restrict__ QK8, uchar* __restrict__ Sb, float alpha) {
    __shared__ uchar smem[49152];
    int b0 = blockIdx.x;                             // 0..511
    for (int it = 0; it < 4; it++) {
        int fid = b0 + it * 512;
        int xcd = fid & 7, j = fid >> 3;             // j 0..255
        int bz = j >> 7;
        int r = j & 127;
        int by = (xcd << 2) | (r >> 5);
        int bx = r & 31;
        gemm_body<128,128,0,6,512>(smem, smem + 3*128*64, bx, by, bz,
            QK8, 1024, sQK, QK8 + 512, 1024, sQK, Sb, N_, sS, nullptr, nullptr, alpha);
        __syncthreads();
    }
}

// ---- PV: Ot = 16*(P@V^T)/rowsum(P). by in [8x,8x+8) reads XCD x's Sb band ----
__global__ __launch_bounds__(256, 3)
void pv_kernel(const uchar* __restrict__ Sb, const uchar* __restrict__ V8,
               uchar* __restrict__ Ot8) {
    __shared__ uchar smem[36864];
    int fid = blockIdx.x;                            // 0..511
    int xcd = fid & 7, j = fid >> 3;                 // j 0..63
    int by = (xcd << 3) | (j & 7);                   // Sb rows [512x, 512x+512)
    int bx = (j >> 3) & 3, bz = j >> 5;
    gemm_body<64,128,0,5,4096>(smem, smem + 3*64*64, bx, by, bz,
        Sb, N_, sS, V8, N_, sV, Ot8, C_, sHn, nullptr, nullptr, 16.f);
}

// ---- proj: out = x + Wp@Ot^T/256 + bp. bx in [4x,4x+4) reads XCD x's Ot band ----
__global__ __launch_bounds__(256, 3)
void proj_kernel(const uchar* __restrict__ Wb3, const uchar* __restrict__ Ot8,
                 const float* __restrict__ x, const float* __restrict__ bp,
                 float* __restrict__ out) {
    __shared__ uchar smem[36864];
    int fid = blockIdx.x;                            // 0..511
    int xcd = fid & 7, j = fid >> 3;                 // j 0..63
    int bx = (xcd << 2) | (j & 3);                   // Ot rows [512x, 512x+512)
    int by = (j >> 2) & 7, bz = j >> 5;
    gemm_body<64,128,2,2,512>(smem, smem + 3*64*64, bx, by, bz,
        Wb3, C_, 0, Ot8, C_, sHn, out, N_, (long long)C_ * N_, bp, x, 1.f/256.f);
}

extern "C" void kernel_launch(void* const* d_in, const int* in_sizes, int n_in,
                              void* d_out, int out_size, void* d_ws, size_t ws_size,
                              hipStream_t stream) {
    const float* x   = (const float*)d_in[0];
    const float* gnw = (const float*)d_in[1];
    const float* gnb = (const float*)d_in[2];
    const float* wq  = (const float*)d_in[3];
    const float* bq  = (const float*)d_in[4];
    const float* wk  = (const float*)d_in[5];
    const float* bk  = (const float*)d_in[6];
    const float* wv  = (const float*)d_in[7];
    const float* bv  = (const float*)d_in[8];
    const float* wp  = (const float*)d_in[9];
    const float* bp  = (const float*)d_in[10];
    float* out = (float*)d_out;
    char*  ws  = (char*)d_ws;

    // workspace layout (~56 MB)
    float* raw  = (float*)(ws + 0);                  // 2 KB  gn stat partials
    float* bqkv = (float*)(ws + 8192);               // 6 KB  bq|bk|bv
    uchar* Wb  = (uchar*)(ws + 65536);               // 1 MB  [4][512][512] fp8 (x16)
    uchar* Hn  = (uchar*)(ws + (2ull  << 20));       // 4 MB  [2][4096][512] fp8
    uchar* QK8 = (uchar*)(ws + (8ull  << 20));       // 8 MB  [2][4096][1024] fp8 (Q|K)
    uchar* V8  = (uchar*)(ws + (16ull << 20));       // 4 MB  [2][512][4096] fp8 (v)
    uchar* Ot8 = (uchar*)(ws + (20ull << 20));       // 4 MB  [2][4096][512] fp8 (16*o)
    uchar* Sb  = (uchar*)(ws + (24ull << 20));       // 32 MB [2][4096][4096] fp8 (P)

    prep_stats<<<PREP_BLOCKS + 256, 256, 0, stream>>>(wq, wk, wv, wp, bq, bk, bv, x,
                                                      Wb, bqkv, raw);
    gn_apply<<<1024, 256, 0, stream>>>(x, raw, gnw, gnb, Hn);

    // QK + V: 512 blocks, 2 GEMM tiles each
    qkv_kernel<<<512, 256, 0, stream>>>(Hn, Wb, QK8, V8, bqkv);

    // P = exp(Q @ K^T / sqrt(512)) -> fp8: 512 blocks x 4 tiles
    s_kernel<<<512, 256, 0, stream>>>(QK8, Sb, 0.044194173824159216f);

    // Ot = 16 * (P @ V^T) / rowsum(P) -> fp8(16*o)   (512 blocks, band-matched)
    pv_kernel<<<512, 256, 0, stream>>>(Sb, V8, Ot8);

    // out = x + (Wp @ Ot^T)/256 + bp   (512 blocks, band-matched)
    proj_kernel<<<512, 256, 0, stream>>>(Wb + 3*WN, Ot8, x, bp, out);
}

// Round 13
// 166.578 us; speedup vs baseline: 4.1545x; 1.0185x over previous
//
#include <hip/hip_runtime.h>
#include <hip/hip_bf16.h>
#include <stdint.h>

typedef float f32x4  __attribute__((ext_vector_type(4)));
typedef float f32x16 __attribute__((ext_vector_type(16)));
typedef int   i32x4  __attribute__((ext_vector_type(4)));
typedef int   i32x8  __attribute__((ext_vector_type(8)));
typedef unsigned char uchar;

#define B_ 2
#define C_ 512
#define N_ 4096
#define G_ 32
#define WN (C_ * C_)
#define PREP_W 1024          // 4*WN/4 float4 loads / 256
#define PREP_BLOCKS 1030     // + 6 bias blocks (1536 floats)

static constexpr long long sHn = (long long)N_ * C_;   // bytes (fp8)
static constexpr long long sQK = (long long)N_ * 1024;
static constexpr long long sV  = (long long)C_ * N_;
static constexpr long long sS  = (long long)N_ * N_;

static __device__ __forceinline__ short f2bf(float f) {
    return __builtin_bit_cast(short, __float2bfloat16(f));
}
static __device__ __forceinline__ uchar f2fp8(float f) {
    return (uchar)(__builtin_amdgcn_cvt_pk_fp8_f32(f, f, 0, false) & 0xff);
}
static __device__ __forceinline__ unsigned pk4fp8(float a, float b, float c, float d) {
    int w = __builtin_amdgcn_cvt_pk_fp8_f32(a, b, 0, false);
    w = __builtin_amdgcn_cvt_pk_fp8_f32(c, d, w, true);
    return (unsigned)w;
}

// async global->LDS DMA, 16 B/lane. LDS dest = wave-uniform base + lane*16.
static __device__ __forceinline__ void async16(uchar* lds_wave_base, const uchar* g) {
    auto l  = (__attribute__((address_space(3))) unsigned int*)(uintptr_t)(lds_wave_base);
    auto gg = (const __attribute__((address_space(1))) unsigned int*)(g);
    __builtin_amdgcn_global_load_lds(gg, l, 16, 0, 0);
}

// ---- merged prep + gn partial stats (no atomics: each stats block owns a slot) ----
__global__ void prep_stats(const float* __restrict__ wq, const float* __restrict__ wk,
                           const float* __restrict__ wv, const float* __restrict__ wp,
                           const float* __restrict__ bq, const float* __restrict__ bk,
                           const float* __restrict__ bv,
                           const float* __restrict__ x,
                           uchar* __restrict__ Wb, float* __restrict__ bqkv,
                           float* __restrict__ raw) {
    if (blockIdx.x < PREP_W) {                       // weights: float4 -> 4 fp8 (x16)
        int i4 = blockIdx.x * 256 + threadIdx.x;     // < 262144
        int base = i4 * 4;
        int wsel = base >> 18;
        const float* src = (wsel == 0) ? wq : (wsel == 1) ? wk : (wsel == 2) ? wv : wp;
        float4 t = *(const float4*)(src + (base & (WN - 1)));
        ((unsigned*)Wb)[i4] = pk4fp8(t.x*16.f, t.y*16.f, t.z*16.f, t.w*16.f);
        return;
    }
    if (blockIdx.x < PREP_BLOCKS) {                  // bqkv[1536] = bq|bk|bv
        int j = (blockIdx.x - PREP_W) * 256 + threadIdx.x;
        if (j < 1536)
            bqkv[j] = (j < C_) ? bq[j] : (j < 2*C_) ? bk[j - C_] : bv[j - 2*C_];
        return;
    }
    const int idx = blockIdx.x - PREP_BLOCKS;        // 0..255
    const int bg = idx >> 2, qt = idx & 3;
    const float4* p = (const float4*)(x + (size_t)bg * 16 * N_ + (size_t)qt * 4 * N_);
    int tid = threadIdx.x;
    float s = 0.f, sq = 0.f;
    #pragma unroll
    for (int rep = 0; rep < 16; rep++) {
        float4 t = p[rep * 256 + tid];
        s  += t.x + t.y + t.z + t.w;
        sq += t.x*t.x + t.y*t.y + t.z*t.z + t.w*t.w;
    }
    __shared__ float rs[256], rq[256];
    rs[tid] = s; rq[tid] = sq;
    __syncthreads();
    for (int h = 128; h > 0; h >>= 1) {
        if (tid < h) { rs[tid] += rs[tid+h]; rq[tid] += rq[tid+h]; }
        __syncthreads();
    }
    if (tid == 0) {
        raw[idx*2+0] = rs[0];
        raw[idx*2+1] = rq[0];
    }
}

// ---- groupnorm apply + transpose: x[b,c,n] fp32 -> Hn[b,n,c] fp8 ----
// Flat grid 1024, XCD-affine: XCD x writes Hn rows [512x, 512x+512).
__global__ void gn_apply(const float* __restrict__ x, const float* __restrict__ raw,
                         const float* __restrict__ gw, const float* __restrict__ gb,
                         uchar* __restrict__ hn) {
    __shared__ uchar t[64 * 68];
    const int fid = blockIdx.x;
    const int xcd = fid & 7, j = fid >> 3;           // j 0..127
    const int n0 = ((xcd << 3) | (j & 7)) * 64;
    const int c0 = ((j >> 3) & 7) * 64;
    const int b  = j >> 6;
    const int lane = threadIdx.x & 63, w = threadIdx.x >> 6;
    const float inv = 1.f / (16.f * N_);
    #pragma unroll
    for (int rep = 0; rep < 16; rep++) {
        int c  = rep * 4 + w;
        int cc = c0 + c;
        int g  = cc >> 4;
        int base = (b*G_ + g) * 8;
        float mean = (raw[base] + raw[base+2] + raw[base+4] + raw[base+6]) * inv;
        float var  = (raw[base+1] + raw[base+3] + raw[base+5] + raw[base+7]) * inv - mean * mean;
        float rstd = rsqrtf(var + 1e-6f);
        float sc = gw[cc] * rstd;
        float bi = gb[cc] - mean * sc;
        float v = x[((size_t)(b*C_ + cc)) * N_ + n0 + lane];
        t[lane*68 + c] = f2fp8(v * sc + bi);
    }
    __syncthreads();
    #pragma unroll
    for (int rep = 0; rep < 16; rep++) {
        int n = rep * 4 + w;
        hn[((size_t)(b*N_ + n0 + n)) * C_ + c0 + lane] = t[n*68 + lane];
    }
}

// ---- fp8 NT GEMM body, MX-scaled MFMA (32x32x64 f8f6f4, unit scales) ----
// 4-buffer LDS ring, 3 tiles prefetched in flight (was 3-ring/2-deep).
// Prologue issues tiles 0-2; STEP(t) consumes buf (t&3), issues tile t+3 into
// buf ((t+3)&3), barrier waits vmcnt(2D) (only the OLDEST tile must land —
// 2 newer tiles stay in flight, AITER-style). Tail drains 2D -> D -> 0.
// Buffer overwrite safe: issue targets the buffer consumed last step, after
// its end-of-step barrier (same invariant as the proven 3-ring).
// SCALE CONVENTION: Wb = fp8(16*w); Hn = fp8(hn); V8 = fp8(v); Sb = fp8(p);
//   Ot8 = fp8(16*o)  [proj: (16w)(16o)/256 = w*o].
// OUT_MODE: 2 fp32+res, 3 fp8, 5 PV rowsum-via-ones-MFMA, 6 S->P no-max exp.
template<int BM, int BN, int BIAS_MODE, int OUT_MODE, int K>
static __device__ __forceinline__ void gemm_body(
        uchar* As_, uchar* Bs_,                      // [4][BM*64], [4][BN*64]
        int bx, int by, int bz,
        const uchar* __restrict__ A, int lda, long long sAz,
        const uchar* __restrict__ Bm, int ldb, long long sBz,
        void* __restrict__ Cv, int ldc, long long sCz,
        const float* __restrict__ bias,
        const void* __restrict__ resv,
        float alpha) {
    constexpr int MI = BM / 64;
    constexpr int NI = BN / 64;
    constexpr int AC = BM / 64;
    constexpr int BC = BN / 64;
    constexpr int T  = K / 64;                       // 8 or 64 (both ≡ 0 mod 4)
    constexpr int D  = (BM + BN) / 64;               // DMAs per wave per tile
    constexpr unsigned WAIT2D = 0xF70u | (2 * D);    // vmcnt(2D) — oldest tile done
    constexpr unsigned WAITD  = 0xF70u | D;          // vmcnt(D)
    constexpr unsigned WAIT0  = 0xF70u;              // vmcnt(0)
    constexpr int ASZ = BM * 64, BSZ = BN * 64;

    const int tid  = threadIdx.x;
    const int lane = tid & 63;
    const int wid  = tid >> 6;
    const int wr   = wid >> 1;
    const int wc   = wid & 1;
    const int m0 = by * BM;
    const int n0 = bx * BN;

    const int r  = tid >> 2;
    const int gc = (tid & 3) ^ ((r >> 1) & 3);
    const uchar* Ap = A  + sAz * bz + (size_t)(m0 + r) * lda + gc * 16;
    const uchar* Bp = Bm + sBz * bz + (size_t)(n0 + r) * ldb + gc * 16;

    f32x16 acc[MI][NI];
    #pragma unroll
    for (int i = 0; i < MI; i++)
        #pragma unroll
        for (int j = 0; j < NI; j++)
            #pragma unroll
            for (int e = 0; e < 16; e++)
                acc[i][j][e] = 0.f;

    f32x16 accs[MI];
    i32x8 ones8;
    if (OUT_MODE == 5) {
        #pragma unroll
        for (int i = 0; i < MI; i++)
            #pragma unroll
            for (int e = 0; e < 16; e++)
                accs[i][e] = 0.f;
        #pragma unroll
        for (int e = 0; e < 8; e++)
            ones8[e] = 0x38383838;                   // fp8 e4m3 1.0 x4
    }

    const int rl = lane & 31;
    const int hk = (lane >> 5) * 2;

    #define ISSUE(IB, u) do { size_t _kb = (size_t)(u) * 64; \
        _Pragma("unroll") \
        for (int c = 0; c < AC; c++) \
            async16(As_ + (IB)*ASZ + c * 4096 + wid * 1024, Ap + (size_t)c * 64 * lda + _kb); \
        _Pragma("unroll") \
        for (int c = 0; c < BC; c++) \
            async16(Bs_ + (IB)*BSZ + c * 4096 + wid * 1024, Bp + (size_t)c * 64 * ldb + _kb); } while (0)

    #define STEP(Bf, DO_ISSUE, IB, u, DO_BAR, WIMM) do { \
        i32x8 af[MI], bf[NI]; \
        _Pragma("unroll") \
        for (int i = 0; i < MI; i++) { \
            int ar = wr*(BM/2) + i*32 + rl; \
            int ao = ar*64 + ((hk ^ ((ar>>1)&3)) << 4); \
            *(i32x4*)&af[i]       = *(const i32x4*)(As_ + (Bf)*ASZ + ao); \
            *(((i32x4*)&af[i])+1) = *(const i32x4*)(As_ + (Bf)*ASZ + (ao ^ 16)); \
        } \
        _Pragma("unroll") \
        for (int i = 0; i < NI; i++) { \
            int br = wc*(BN/2) + i*32 + rl; \
            int bo = br*64 + ((hk ^ ((br>>1)&3)) << 4); \
            *(i32x4*)&bf[i]       = *(const i32x4*)(Bs_ + (Bf)*BSZ + bo); \
            *(((i32x4*)&bf[i])+1) = *(const i32x4*)(Bs_ + (Bf)*BSZ + (bo ^ 16)); \
        } \
        if (DO_ISSUE) ISSUE(IB, u); \
        _Pragma("unroll") \
        for (int mi = 0; mi < MI; mi++) \
            _Pragma("unroll") \
            for (int ni = 0; ni < NI; ni++) \
                acc[mi][ni] = __builtin_amdgcn_mfma_scale_f32_32x32x64_f8f6f4( \
                    af[mi], bf[ni], acc[mi][ni], 0, 0, 0, 127, 0, 127); \
        if (OUT_MODE == 5) { \
            _Pragma("unroll") \
            for (int mi = 0; mi < MI; mi++) \
                accs[mi] = __builtin_amdgcn_mfma_scale_f32_32x32x64_f8f6f4( \
                    af[mi], ones8, accs[mi], 0, 0, 0, 127, 0, 127); \
        } \
        if (DO_BAR) { __builtin_amdgcn_s_waitcnt(WIMM); __builtin_amdgcn_s_barrier(); } \
    } while (0)

    // prologue: tiles 0,1,2 in flight; wait only the oldest (vmcnt(2D)), barrier
    ISSUE(0, 0);
    ISSUE(1, 1);
    ISSUE(2, 2);
    __builtin_amdgcn_s_waitcnt(WAIT2D);
    __builtin_amdgcn_s_barrier();

    constexpr int Gm = (T - 4) / 4;                  // T=8 -> 1, T=64 -> 15
    for (int m = 0; m < Gm; m++) {
        STEP(0, 1, 3, m*4 + 3, 1, WAIT2D);
        STEP(1, 1, 0, m*4 + 4, 1, WAIT2D);
        STEP(2, 1, 1, m*4 + 5, 1, WAIT2D);
        STEP(3, 1, 2, m*4 + 6, 1, WAIT2D);
    }
    // remainder issue step t=T-4 (buf0), issues last tile T-1 into buf3
    STEP(0, 1, 3, T-1, 1, WAIT2D);
    // tail: drain 2 -> 1 -> 0 tiles in flight
    STEP(1, 0, 0, 0, 1, WAITD);
    STEP(2, 0, 0, 0, 1, WAIT0);
    STEP(3, 0, 0, 0, 0, 0);
    #undef ISSUE
    #undef STEP

    const int rh = (lane >> 5) * 4;

    if (OUT_MODE == 6) {
        #pragma unroll
        for (int mi = 0; mi < MI; mi++) {
            #pragma unroll
            for (int ni = 0; ni < NI; ni++) {
                int cc = n0 + wc*(BN/2) + ni*32 + rl;
                #pragma unroll
                for (int e = 0; e < 16; e++) {
                    int g = e >> 2, r4 = e & 3;
                    int rr = m0 + wr*(BM/2) + mi*32 + g*8 + rh + r4;
                    float p = fminf(__expf(acc[mi][ni][e] * alpha), 448.f);
                    long long idx = sCz * bz + (long long)rr * ldc + cc;
                    ((uchar*)Cv)[idx] = f2fp8(p);
                }
            }
        }
        return;
    }

    if (OUT_MODE == 5) {
        #pragma unroll
        for (int mi = 0; mi < MI; mi++) {
            #pragma unroll
            for (int e = 0; e < 16; e++) {
                int g = e >> 2, r4 = e & 3;
                int rr = m0 + wr*(BM/2) + mi*32 + g*8 + rh + r4;
                float rinv = __builtin_amdgcn_rcpf(accs[mi][e]) * alpha;
                #pragma unroll
                for (int ni = 0; ni < NI; ni++) {
                    int cc = n0 + wc*(BN/2) + ni*32 + rl;
                    long long idx = sCz * bz + (long long)rr * ldc + cc;
                    ((uchar*)Cv)[idx] = f2fp8(acc[mi][ni][e] * rinv);
                }
            }
        }
        return;
    }

    #pragma unroll
    for (int mi = 0; mi < MI; mi++) {
        #pragma unroll
        for (int ni = 0; ni < NI; ni++) {
            int cc = n0 + wc*(BN/2) + ni*32 + rl;
            float cb = (BIAS_MODE == 1) ? bias[cc] : 0.f;
            #pragma unroll
            for (int g = 0; g < 4; g++) {
                #pragma unroll
                for (int r4 = 0; r4 < 4; r4++) {
                    int rr = m0 + wr*(BM/2) + mi*32 + g*8 + rh + r4;
                    float val = acc[mi][ni][g*4 + r4] * alpha + cb;
                    if (BIAS_MODE == 2) val += bias[rr];
                    long long idx = sCz * bz + (long long)rr * ldc + cc;
                    if (OUT_MODE == 0)      ((short*)Cv)[idx] = f2bf(val);
                    else if (OUT_MODE == 2) ((float*)Cv)[idx] = val + ((const float*)resv)[idx];
                    else                    ((uchar*)Cv)[idx] = f2fp8(val);
                }
            }
        }
    }
}

// ---- merged QKV: blocks 0-511 QK GEMM; blocks 512-1023 V GEMM (R9 decode) ----
__global__ __launch_bounds__(256, 2)
void qkv_kernel(const uchar* __restrict__ Hn, const uchar* __restrict__ Wb,
                uchar* __restrict__ QK8, uchar* __restrict__ V8,
                const float* __restrict__ bqkv) {
    __shared__ uchar smem[65536];
    int fid = blockIdx.x;
    if (fid < 512) {
        int xcd = fid & 7, j = fid >> 3;             // j 0..63
        int by = (xcd << 2) | (j & 3);               // Q rows [512x, 512x+512)
        int bx = (j >> 2) & 7, bz = j >> 5;
        gemm_body<128,128,1,3,512>(smem, smem + 4*128*64, bx, by, bz,
            Hn, C_, sHn, Wb, C_, 0, QK8, 1024, sQK, bqkv, nullptr, 1.f/16.f);
    } else {
        int f2 = fid - 512;
        int xcd = f2 & 7, j = f2 >> 3;
        int bx = (xcd << 2) | (j & 3);               // K-dim rows [512x, 512x+512)
        int by = (j >> 2) & 7, bz = j >> 5;
        gemm_body<64,128,2,3,512>(smem, smem + 4*64*64, bx, by, bz,
            Wb + 2*WN, C_, 0, Hn, C_, sHn, V8, N_, sV, bqkv + 1024, nullptr, 1.f/16.f);
    }
}

// ---- S: P = exp(QK^T/sqrt(512)) -> fp8. XCD x owns Sb rows [512x, 512x+512) ----
__global__ __launch_bounds__(256, 2)
void s_kernel(const uchar* __restrict__ QK8, uchar* __restrict__ Sb, float alpha) {
    __shared__ uchar smem[65536];
    int fid = blockIdx.x;                            // 0..2047
    int xcd = fid & 7, j = fid >> 3;                 // j 0..255
    int bz = j >> 7;
    int r = j & 127;
    int by = (xcd << 2) | (r >> 5);
    int bx = r & 31;
    gemm_body<128,128,0,6,512>(smem, smem + 4*128*64, bx, by, bz,
        QK8, 1024, sQK, QK8 + 512, 1024, sQK, Sb, N_, sS, nullptr, nullptr, alpha);
}

// ---- PV: Ot = 16*(P@V^T)/rowsum(P). by in [8x,8x+8) reads XCD x's Sb band ----
__global__ __launch_bounds__(256, 3)
void pv_kernel(const uchar* __restrict__ Sb, const uchar* __restrict__ V8,
               uchar* __restrict__ Ot8) {
    __shared__ uchar smem[49152];
    int fid = blockIdx.x;                            // 0..511
    int xcd = fid & 7, j = fid >> 3;                 // j 0..63
    int by = (xcd << 3) | (j & 7);                   // Sb rows [512x, 512x+512)
    int bx = (j >> 3) & 3, bz = j >> 5;
    gemm_body<64,128,0,5,4096>(smem, smem + 4*64*64, bx, by, bz,
        Sb, N_, sS, V8, N_, sV, Ot8, C_, sHn, nullptr, nullptr, 16.f);
}

// ---- proj: out = x + Wp@Ot^T/256 + bp. bx in [4x,4x+4) reads XCD x's Ot band ----
__global__ __launch_bounds__(256, 3)
void proj_kernel(const uchar* __restrict__ Wb3, const uchar* __restrict__ Ot8,
                 const float* __restrict__ x, const float* __restrict__ bp,
                 float* __restrict__ out) {
    __shared__ uchar smem[49152];
    int fid = blockIdx.x;                            // 0..511
    int xcd = fid & 7, j = fid >> 3;                 // j 0..63
    int bx = (xcd << 2) | (j & 3);                   // Ot rows [512x, 512x+512)
    int by = (j >> 2) & 7, bz = j >> 5;
    gemm_body<64,128,2,2,512>(smem, smem + 4*64*64, bx, by, bz,
        Wb3, C_, 0, Ot8, C_, sHn, out, N_, (long long)C_ * N_, bp, x, 1.f/256.f);
}

extern "C" void kernel_launch(void* const* d_in, const int* in_sizes, int n_in,
                              void* d_out, int out_size, void* d_ws, size_t ws_size,
                              hipStream_t stream) {
    const float* x   = (const float*)d_in[0];
    const float* gnw = (const float*)d_in[1];
    const float* gnb = (const float*)d_in[2];
    const float* wq  = (const float*)d_in[3];
    const float* bq  = (const float*)d_in[4];
    const float* wk  = (const float*)d_in[5];
    const float* bk  = (const float*)d_in[6];
    const float* wv  = (const float*)d_in[7];
    const float* bv  = (const float*)d_in[8];
    const float* wp  = (const float*)d_in[9];
    const float* bp  = (const float*)d_in[10];
    float* out = (float*)d_out;
    char*  ws  = (char*)d_ws;

    // workspace layout (~56 MB)
    float* raw  = (float*)(ws + 0);                  // 2 KB  gn stat partials
    float* bqkv = (float*)(ws + 8192);               // 6 KB  bq|bk|bv
    uchar* Wb  = (uchar*)(ws + 65536);               // 1 MB  [4][512][512] fp8 (x16)
    uchar* Hn  = (uchar*)(ws + (2ull  << 20));       // 4 MB  [2][4096][512] fp8
    uchar* QK8 = (uchar*)(ws + (8ull  << 20));       // 8 MB  [2][4096][1024] fp8 (Q|K)
    uchar* V8  = (uchar*)(ws + (16ull << 20));       // 4 MB  [2][512][4096] fp8 (v)
    uchar* Ot8 = (uchar*)(ws + (20ull << 20));       // 4 MB  [2][4096][512] fp8 (16*o)
    uchar* Sb  = (uchar*)(ws + (24ull << 20));       // 32 MB [2][4096][4096] fp8 (P)

    prep_stats<<<PREP_BLOCKS + 256, 256, 0, stream>>>(wq, wk, wv, wp, bq, bk, bv, x,
                                                      Wb, bqkv, raw);
    gn_apply<<<1024, 256, 0, stream>>>(x, raw, gnw, gnb, Hn);

    // QK + V in one heterogeneous launch (1024 blocks)
    qkv_kernel<<<1024, 256, 0, stream>>>(Hn, Wb, QK8, V8, bqkv);

    // P = exp(Q @ K^T / sqrt(512)) -> fp8   (2048 blocks, XCD-banded)
    s_kernel<<<2048, 256, 0, stream>>>(QK8, Sb, 0.044194173824159216f);

    // Ot = 16 * (P @ V^T) / rowsum(P) -> fp8(16*o)   (512 blocks, band-matched)
    pv_kernel<<<512, 256, 0, stream>>>(Sb, V8, Ot8);

    // out = x + (Wp @ Ot^T)/256 + bp   (512 blocks, band-matched)
    proj_kernel<<<512, 256, 0, stream>>>(Wb + 3*WN, Ot8, x, bp, out);
}